// Round 4
// baseline (250.732 us; speedup 1.0000x reference)
//
#include <hip/hip_runtime.h>
#include <math.h>

#define TMAXV 20.0f
#define L2E 1.4426950408889634f
#define LN2 0.6931471805599453f

typedef __fp16 h2 __attribute__((ext_vector_type(2)));

__device__ __forceinline__ float fexp2(float x){ return __builtin_amdgcn_exp2f(x); }
__device__ __forceinline__ float flog2(float x){ return __builtin_amdgcn_logf(x); }
__device__ __forceinline__ float frcp(float x){ return __builtin_amdgcn_rcpf(x); }
__device__ __forceinline__ float fsig(float x){ return frcp(1.0f + fexp2(-x * L2E)); }
__device__ __forceinline__ float ftanh_(float x){ return 1.0f - 2.0f * frcp(1.0f + fexp2(2.0f * x * L2E)); }

template <int CTRL>
__device__ __forceinline__ float dppmov(float x) {
    return __int_as_float(__builtin_amdgcn_update_dpp(0, __float_as_int(x), CTRL, 0xf, 0xf, false));
}
// wave64 sum -> uniform (row_shr chain + row_bcast, verified round 2)
__device__ __forceinline__ float wsum(float x) {
    x += dppmov<0x111>(x);  // row_shr:1
    x += dppmov<0x112>(x);  // row_shr:2
    x += dppmov<0x114>(x);  // row_shr:4
    x += dppmov<0x118>(x);  // row_shr:8
    x += dppmov<0x142>(x);  // row_bcast:15
    x += dppmov<0x143>(x);  // row_bcast:31
    return __int_as_float(__builtin_amdgcn_readlane(__float_as_int(x), 63));
}
__device__ __forceinline__ float wsum_shfl(float v) {
    v += __shfl_xor(v, 1);  v += __shfl_xor(v, 2);  v += __shfl_xor(v, 4);
    v += __shfl_xor(v, 8);  v += __shfl_xor(v, 16); v += __shfl_xor(v, 32);
    return v;
}

// grid = 256 blocks x 256 threads, all co-resident (<=1 block/CU by capacity):
//  blocks [0,64):    LSTM rollout, wave 0 only. Single-wave design: lane l owns
//                    all 4 gate rows of hidden unit l -> cell update fully in-lane,
//                    hx broadcast via v_readlane, weights f16-packed (v_dot2_f32_f16).
//                    Zero LDS, zero barriers. Writes compacted active times + done++.
//  blocks [64,192):  expert-expert MMD term (input-only, runs concurrently).
//  blocks [192,256): spin on done==64, then ll + le over COMPACTED learner points.
__global__ __launch_bounds__(256) void fused(
    const float* __restrict__ up,    // [64,128] uniform pool
    const float* __restrict__ te,    // [64,128] expert times
    const float* __restrict__ Wih,   // [256]
    const float* __restrict__ Whh,   // [256,64]
    const float* __restrict__ bih,   // [256]
    const float* __restrict__ bhh,   // [256]
    const float* __restrict__ Vw,    // [64]
    const float* __restrict__ Vb,    // [1]
    unsigned int* __restrict__ hdr,  // ws: [0]=count of compacted pts, [1]=done blocks
    float* __restrict__ comp,        // ws+16: compacted learner times (<=8192)
    float* __restrict__ out)         // [1] loss
{
    __shared__ float2 qbuf[2048];
    const int bid = blockIdx.x;
    const int tid = threadIdx.x;

    if (bid < 64) {
        if (tid >= 64) return;       // single wave; waves 1-3 exit (wave-uniform)
        const int l = tid;

        // 4 gate rows (i,f,g,o for h=l) as f16 pairs: 128 VGPRs
        h2 w[4][32];
        #pragma unroll
        for (int r = 0; r < 4; ++r) {
            const float4* rp = (const float4*)(Whh + (r * 64 + l) * 64);
            #pragma unroll
            for (int j = 0; j < 16; ++j) {
                float4 q = rp[j];
                w[r][2 * j]     = __builtin_amdgcn_cvt_pkrtz(q.x, q.y);
                w[r][2 * j + 1] = __builtin_amdgcn_cvt_pkrtz(q.z, q.w);
            }
        }
        float bias[4], wih[4];
        #pragma unroll
        for (int r = 0; r < 4; ++r) {
            bias[r] = bih[r * 64 + l] + bhh[r * 64 + l];
            wih[r]  = Wih[r * 64 + l];
        }
        const float vwl = Vw[l];
        const float vb  = Vb[0];
        float lu0 = -flog2(up[bid * 128 + l]) * LN2;
        float lu1 = -flog2(up[bid * 128 + 64 + l]) * LN2;

        // step 0: hx=0 -> sigma = elu(vb)+1 (elu(x)+1 == exp(x) for x<=0)
        float sg0 = (vb > 0.0f) ? (vb + 1.0f) : fexp2(vb * L2E);
        float cum = __int_as_float(__builtin_amdgcn_readlane(__float_as_int(lu0), 0)) * frcp(sg0);
        float h0 = (l == 0) ? cum : 1e30f;   // t[s] for s = l
        float h1 = 1e30f;                    // t[s] for s = 64+l
        float hx = 0.0f, cx = 0.0f;

        for (int s = 0; s < 127; ++s) {
            // pack (hx[2j], hx[2j+1]) on even lanes: quad_perm pair-swap + pkrtz
            float hxn = dppmov<0xB1>(hx);    // quad_perm [1,0,3,2]
            h2 hp = __builtin_amdgcn_cvt_pkrtz(hx, hxn);
            int hpi = __builtin_bit_cast(int, hp);

            float d0 = 0.f, d1 = 0.f, d2 = 0.f, d3 = 0.f;
            #pragma unroll
            for (int j = 0; j < 32; ++j) {
                h2 b = __builtin_bit_cast(h2, __builtin_amdgcn_readlane(hpi, 2 * j));
                d0 = __builtin_amdgcn_fdot2(w[0][j], b, d0, false);
                d1 = __builtin_amdgcn_fdot2(w[1][j], b, d1, false);
                d2 = __builtin_amdgcn_fdot2(w[2][j], b, d2, false);
                d3 = __builtin_amdgcn_fdot2(w[3][j], b, d3, false);
            }
            float gi = fmaf(cum, wih[0], d0) + bias[0];
            float gf = fmaf(cum, wih[1], d1) + bias[1];
            float gg = fmaf(cum, wih[2], d2) + bias[2];
            float go = fmaf(cum, wih[3], d3) + bias[3];
            cx = fsig(gf) * cx + fsig(gi) * ftanh_(gg);
            hx = fsig(go) * ftanh_(cx);

            float tot = wsum(hx * vwl);
            float xx  = tot + vb;
            float sg  = (xx > 0.0f) ? (xx + 1.0f) : fexp2(xx * L2E);
            int idx = s + 1;
            float lun = __int_as_float(__builtin_amdgcn_readlane(
                            __float_as_int(idx < 64 ? lu0 : lu1), idx & 63));
            cum += lun * frcp(sg);
            h0 = (l == idx)      ? cum : h0;
            h1 = (l == idx - 64) ? cum : h1;
        }

        // compacted append: times monotone increasing -> actives are a prefix
        unsigned long long b0 = __ballot(h0 < TMAXV);
        unsigned long long b1 = __ballot(h1 < TMAXV);
        int n0 = __popcll(b0), n1 = __popcll(b1);
        int base = 0;
        if (l == 0) base = (int)atomicAdd(&hdr[0], (unsigned)(n0 + n1));
        base = __shfl(base, 0);
        if (h0 < TMAXV) comp[base + l] = h0;
        if (h1 < TMAXV) comp[base + 64 + l] = h1;   // only when n0==64 (monotone)
        __threadfence();
        if (l == 0) atomicAdd(&hdr[1], 1u);
    } else if (bid < 192) {
        // ---------------- expert-expert MMD term ----------------
        const int eb = bid - 64;         // 0..127
        const int pc = eb & 31;
        const int qs = eb >> 5;
        const int p = pc * 256 + tid;
        const float tp = te[p];
        const float mp = (tp < TMAXV && tp > 0.0f) ? 1.0f : 0.0f;
        const int q0 = qs * 2048;
        for (int i = tid; i < 2048; i += 256) {
            float tq = te[q0 + i];
            float mq = (tq < TMAXV && tq > 0.0f) ? 1.0f : 0.0f;
            qbuf[i] = make_float2(tq, mq);
        }
        __syncthreads();
        float acc = 0.0f;
        #pragma unroll 4
        for (int i = 0; i < 2048; ++i) {
            float2 q = qbuf[i];
            float d = tp - q.x;
            acc = fmaf(q.y, fexp2(d * d * (-L2E)), acc);
        }
        acc *= mp;
        acc = wsum_shfl(acc);
        if ((tid & 63) == 0) atomicAdd(out, acc);
    } else {
        // ---------------- ll + le on compacted learner points ----------------
        if (tid == 0) {
            while (atomicAdd(&hdr[1], 0u) < 64u) __builtin_amdgcn_s_sleep(16);
        }
        __syncthreads();
        __threadfence();   // acquire: invalidate caches before reading comp
        const int n = (int)*(volatile unsigned int*)&hdr[0];
        const int gid = (bid - 192) * 256 + tid;   // 0..16383
        const int pg = gid >> 5;                   // p-group (32 lanes each)
        const int sl = gid & 31;
        float acc = 0.0f;
        for (int pi = pg; pi < n; pi += 512) {
            float tp = comp[pi];                   // active by construction (m=1)
            float all_ = 0.0f, ale = 0.0f;
            for (int j = sl; j < 8192; j += 32) {
                float t = te[j];
                float m = (t < TMAXV && t > 0.0f) ? 1.0f : 0.0f;
                float d = tp - t;
                ale = fmaf(m, fexp2(d * d * (-L2E)), ale);
            }
            for (int j = sl; j < n; j += 32) {
                float d = tp - comp[j];
                all_ += fexp2(d * d * (-L2E));
            }
            acc += all_ - 2.0f * ale;
        }
        acc = wsum_shfl(acc);
        if ((tid & 63) == 0) atomicAdd(out, acc);
    }
}

extern "C" void kernel_launch(void* const* d_in, const int* in_sizes, int n_in,
                              void* d_out, int out_size, void* d_ws, size_t ws_size,
                              hipStream_t stream) {
    const float* up  = (const float*)d_in[0];
    const float* te  = (const float*)d_in[1];
    const float* Wih = (const float*)d_in[2];
    const float* Whh = (const float*)d_in[3];
    const float* bih = (const float*)d_in[4];
    const float* bhh = (const float*)d_in[5];
    const float* Vw  = (const float*)d_in[6];
    const float* Vb  = (const float*)d_in[7];
    unsigned int* hdr = (unsigned int*)d_ws;
    float* comp = (float*)d_ws + 4;
    float* out = (float*)d_out;

    (void)hipMemsetAsync(d_ws, 0, 16, stream);
    (void)hipMemsetAsync(d_out, 0, 4, stream);
    hipLaunchKernelGGL(fused, dim3(256), dim3(256), 0, stream,
                       up, te, Wih, Whh, bih, bhh, Vw, Vb, hdr, comp, out);
}

// Round 5
// 248.435 us; speedup vs baseline: 1.0092x; 1.0092x over previous
//
#include <hip/hip_runtime.h>
#include <math.h>

#define TMAXV 20.0f
#define L2E 1.4426950408889634f
#define LN2 0.6931471805599453f

typedef __fp16 h2 __attribute__((ext_vector_type(2)));

__device__ __forceinline__ float fexp2(float x){ return __builtin_amdgcn_exp2f(x); }
__device__ __forceinline__ float flog2(float x){ return __builtin_amdgcn_logf(x); }
__device__ __forceinline__ float frcp(float x){ return __builtin_amdgcn_rcpf(x); }
__device__ __forceinline__ float fsig(float x){ return frcp(1.0f + fexp2(-x * L2E)); }
__device__ __forceinline__ float ftanh_(float x){ return 1.0f - 2.0f * frcp(1.0f + fexp2(2.0f * x * L2E)); }

template <int CTRL>
__device__ __forceinline__ float dppmov(float x) {
    return __int_as_float(__builtin_amdgcn_update_dpp(0, __float_as_int(x), CTRL, 0xf, 0xf, false));
}
// wave64 sum -> uniform (row_shr chain + row_bcast, verified round 2)
__device__ __forceinline__ float wsum(float x) {
    x += dppmov<0x111>(x);  // row_shr:1
    x += dppmov<0x112>(x);  // row_shr:2
    x += dppmov<0x114>(x);  // row_shr:4
    x += dppmov<0x118>(x);  // row_shr:8
    x += dppmov<0x142>(x);  // row_bcast:15
    x += dppmov<0x143>(x);  // row_bcast:31
    return __int_as_float(__builtin_amdgcn_readlane(__float_as_int(x), 63));
}
__device__ __forceinline__ float wsum_shfl(float v) {
    v += __shfl_xor(v, 1);  v += __shfl_xor(v, 2);  v += __shfl_xor(v, 4);
    v += __shfl_xor(v, 8);  v += __shfl_xor(v, 16); v += __shfl_xor(v, 32);
    return v;
}

// grid = 256 blocks x 256 threads, 1 block/CU (4 waves = 1 wave/EU).
// amdgpu_waves_per_eu(1,1): zero occupancy cost at this grid shape, and it
// raises the VGPR budget to ~512 so the 128-VGPR weight array stays resident
// (round 4: VGPR_Count=88 -> weights spilled to scratch -> 3470 cyc/step).
//  blocks [0,64):    LSTM rollout, wave 0 only; lane l owns all 4 gate rows of
//                    hidden unit l; hx broadcast via v_readlane; f16 fdot2.
//  blocks [64,192):  expert-expert MMD term (input-only, runs concurrently).
//  blocks [192,256): spin on done==64, then ll + le over COMPACTED learner pts.
__global__ __launch_bounds__(256)
__attribute__((amdgpu_waves_per_eu(1, 1)))
void fused(
    const float* __restrict__ up,    // [64,128] uniform pool
    const float* __restrict__ te,    // [64,128] expert times
    const float* __restrict__ Wih,   // [256]
    const float* __restrict__ Whh,   // [256,64]
    const float* __restrict__ bih,   // [256]
    const float* __restrict__ bhh,   // [256]
    const float* __restrict__ Vw,    // [64]
    const float* __restrict__ Vb,    // [1]
    unsigned int* __restrict__ hdr,  // ws: [0]=count of compacted pts, [1]=done blocks
    float* __restrict__ comp,        // ws+16: compacted learner times (<=8192)
    float* __restrict__ out)         // [1] loss
{
    __shared__ float2 qbuf[2048];
    const int bid = blockIdx.x;
    const int tid = threadIdx.x;

    if (bid < 64) {
        if (tid >= 64) return;       // single wave; waves 1-3 exit (wave-uniform)
        const int l = tid;

        // 4 gate rows (i,f,g,o for h=l) as packed f16 pairs in int regs (128 VGPRs)
        int wi[4][32];
        #pragma unroll
        for (int r = 0; r < 4; ++r) {
            const float4* rp = (const float4*)(Whh + (r * 64 + l) * 64);
            #pragma unroll
            for (int j = 0; j < 16; ++j) {
                float4 q = rp[j];
                wi[r][2 * j]     = __builtin_bit_cast(int, __builtin_amdgcn_cvt_pkrtz(q.x, q.y));
                wi[r][2 * j + 1] = __builtin_bit_cast(int, __builtin_amdgcn_cvt_pkrtz(q.z, q.w));
            }
        }
        float bias[4], wih[4];
        #pragma unroll
        for (int r = 0; r < 4; ++r) {
            bias[r] = bih[r * 64 + l] + bhh[r * 64 + l];
            wih[r]  = Wih[r * 64 + l];
        }
        const float vwl = Vw[l];
        const float vb  = Vb[0];
        float lu0 = -flog2(up[bid * 128 + l]) * LN2;
        float lu1 = -flog2(up[bid * 128 + 64 + l]) * LN2;

        // step 0: hx=0 -> sigma = elu(vb)+1 (elu(x)+1 == exp(x) for x<=0)
        float sg0 = (vb > 0.0f) ? (vb + 1.0f) : fexp2(vb * L2E);
        float cum = __int_as_float(__builtin_amdgcn_readlane(__float_as_int(lu0), 0)) * frcp(sg0);
        float h0 = (l == 0) ? cum : 1e30f;   // t[s] for s = l
        float h1 = 1e30f;                    // t[s] for s = 64+l
        float hx = 0.0f, cx = 0.0f;

        for (int s = 0; s < 127; ++s) {
            // pack (hx[2j], hx[2j+1]) on even lanes: quad_perm pair-swap + pkrtz
            float hxn = dppmov<0xB1>(hx);    // quad_perm [1,0,3,2]
            int hpi = __builtin_bit_cast(int, __builtin_amdgcn_cvt_pkrtz(hx, hxn));

            float d0 = 0.f, d1 = 0.f, d2 = 0.f, d3 = 0.f;
            #pragma unroll
            for (int j = 0; j < 32; ++j) {
                h2 b = __builtin_bit_cast(h2, __builtin_amdgcn_readlane(hpi, 2 * j));
                d0 = __builtin_amdgcn_fdot2(__builtin_bit_cast(h2, wi[0][j]), b, d0, false);
                d1 = __builtin_amdgcn_fdot2(__builtin_bit_cast(h2, wi[1][j]), b, d1, false);
                d2 = __builtin_amdgcn_fdot2(__builtin_bit_cast(h2, wi[2][j]), b, d2, false);
                d3 = __builtin_amdgcn_fdot2(__builtin_bit_cast(h2, wi[3][j]), b, d3, false);
            }
            float gi = fmaf(cum, wih[0], d0) + bias[0];
            float gf = fmaf(cum, wih[1], d1) + bias[1];
            float gg = fmaf(cum, wih[2], d2) + bias[2];
            float go = fmaf(cum, wih[3], d3) + bias[3];
            cx = fsig(gf) * cx + fsig(gi) * ftanh_(gg);
            hx = fsig(go) * ftanh_(cx);

            float tot = wsum(hx * vwl);
            float xx  = tot + vb;
            float sg  = (xx > 0.0f) ? (xx + 1.0f) : fexp2(xx * L2E);
            int idx = s + 1;
            float lun = __int_as_float(__builtin_amdgcn_readlane(
                            __float_as_int(idx < 64 ? lu0 : lu1), idx & 63));
            cum += lun * frcp(sg);
            h0 = (l == idx)      ? cum : h0;
            h1 = (l == idx - 64) ? cum : h1;
        }

        // compacted append: times monotone increasing -> actives are a prefix
        unsigned long long b0 = __ballot(h0 < TMAXV);
        unsigned long long b1 = __ballot(h1 < TMAXV);
        int n0 = __popcll(b0), n1 = __popcll(b1);
        int base = 0;
        if (l == 0) base = (int)atomicAdd(&hdr[0], (unsigned)(n0 + n1));
        base = __shfl(base, 0);
        if (h0 < TMAXV) comp[base + l] = h0;
        if (h1 < TMAXV) comp[base + 64 + l] = h1;   // only when n0==64 (monotone)
        __threadfence();
        if (l == 0) atomicAdd(&hdr[1], 1u);
    } else if (bid < 192) {
        // ---------------- expert-expert MMD term ----------------
        const int eb = bid - 64;         // 0..127
        const int pc = eb & 31;
        const int qs = eb >> 5;
        const int p = pc * 256 + tid;
        const float tp = te[p];
        const float mp = (tp < TMAXV && tp > 0.0f) ? 1.0f : 0.0f;
        const int q0 = qs * 2048;
        for (int i = tid; i < 2048; i += 256) {
            float tq = te[q0 + i];
            float mq = (tq < TMAXV && tq > 0.0f) ? 1.0f : 0.0f;
            qbuf[i] = make_float2(tq, mq);
        }
        __syncthreads();
        float acc = 0.0f;
        #pragma unroll 4
        for (int i = 0; i < 2048; ++i) {
            float2 q = qbuf[i];
            float d = tp - q.x;
            acc = fmaf(q.y, fexp2(d * d * (-L2E)), acc);
        }
        acc *= mp;
        acc = wsum_shfl(acc);
        if ((tid & 63) == 0) atomicAdd(out, acc);
    } else {
        // ---------------- ll + le on compacted learner points ----------------
        if (tid == 0) {
            while (atomicAdd(&hdr[1], 0u) < 64u) __builtin_amdgcn_s_sleep(16);
        }
        __syncthreads();
        __threadfence();   // acquire: invalidate caches before reading comp
        const int n = (int)*(volatile unsigned int*)&hdr[0];
        const int gid = (bid - 192) * 256 + tid;   // 0..16383
        const int pg = gid >> 5;                   // p-group (32 lanes each)
        const int sl = gid & 31;
        float acc = 0.0f;
        for (int pi = pg; pi < n; pi += 512) {
            float tp = comp[pi];                   // active by construction (m=1)
            float all_ = 0.0f, ale = 0.0f;
            for (int j = sl; j < 8192; j += 32) {
                float t = te[j];
                float m = (t < TMAXV && t > 0.0f) ? 1.0f : 0.0f;
                float d = tp - t;
                ale = fmaf(m, fexp2(d * d * (-L2E)), ale);
            }
            for (int j = sl; j < n; j += 32) {
                float d = tp - comp[j];
                all_ += fexp2(d * d * (-L2E));
            }
            acc += all_ - 2.0f * ale;
        }
        acc = wsum_shfl(acc);
        if ((tid & 63) == 0) atomicAdd(out, acc);
    }
}

extern "C" void kernel_launch(void* const* d_in, const int* in_sizes, int n_in,
                              void* d_out, int out_size, void* d_ws, size_t ws_size,
                              hipStream_t stream) {
    const float* up  = (const float*)d_in[0];
    const float* te  = (const float*)d_in[1];
    const float* Wih = (const float*)d_in[2];
    const float* Whh = (const float*)d_in[3];
    const float* bih = (const float*)d_in[4];
    const float* bhh = (const float*)d_in[5];
    const float* Vw  = (const float*)d_in[6];
    const float* Vb  = (const float*)d_in[7];
    unsigned int* hdr = (unsigned int*)d_ws;
    float* comp = (float*)d_ws + 4;
    float* out = (float*)d_out;

    (void)hipMemsetAsync(d_ws, 0, 16, stream);
    (void)hipMemsetAsync(d_out, 0, 4, stream);
    hipLaunchKernelGGL(fused, dim3(256), dim3(256), 0, stream,
                       up, te, Wih, Whh, bih, bhh, Vw, Vb, hdr, comp, out);
}

// Round 6
// 247.166 us; speedup vs baseline: 1.0144x; 1.0051x over previous
//
#include <hip/hip_runtime.h>
#include <math.h>

#define TMAXV 20.0f
#define L2E 1.4426950408889634f
#define LN2 0.6931471805599453f

typedef __fp16 h2 __attribute__((ext_vector_type(2)));
typedef int vi16 __attribute__((ext_vector_type(16)));

__device__ __forceinline__ float fexp2(float x){ return __builtin_amdgcn_exp2f(x); }
__device__ __forceinline__ float flog2(float x){ return __builtin_amdgcn_logf(x); }
__device__ __forceinline__ float frcp(float x){ return __builtin_amdgcn_rcpf(x); }
__device__ __forceinline__ float fsig(float x){ return frcp(1.0f + fexp2(-x * L2E)); }
__device__ __forceinline__ float ftanh_(float x){ return 1.0f - 2.0f * frcp(1.0f + fexp2(2.0f * x * L2E)); }

template <int CTRL>
__device__ __forceinline__ float dppmov(float x) {
    return __int_as_float(__builtin_amdgcn_update_dpp(0, __float_as_int(x), CTRL, 0xf, 0xf, false));
}
// wave64 sum -> uniform (verified round 2)
__device__ __forceinline__ float wsum(float x) {
    x += dppmov<0x111>(x);  // row_shr:1
    x += dppmov<0x112>(x);  // row_shr:2
    x += dppmov<0x114>(x);  // row_shr:4
    x += dppmov<0x118>(x);  // row_shr:8
    x += dppmov<0x142>(x);  // row_bcast:15
    x += dppmov<0x143>(x);  // row_bcast:31
    return __int_as_float(__builtin_amdgcn_readlane(__float_as_int(x), 63));
}
__device__ __forceinline__ float wsum_shfl(float v) {
    v += __shfl_xor(v, 1);  v += __shfl_xor(v, 2);  v += __shfl_xor(v, 4);
    v += __shfl_xor(v, 8);  v += __shfl_xor(v, 16); v += __shfl_xor(v, 32);
    return v;
}

struct RowW { vi16 a, b; };   // one gate row: 64 f16 weights packed in 32 ints

__device__ __forceinline__ RowW loadrow(const float* __restrict__ Whh, int r, int l) {
    const float4* rp = (const float4*)(Whh + (r * 64 + l) * 64);
    vi16 A, B;
    #pragma unroll
    for (int j = 0; j < 8; ++j) {
        float4 q = rp[j];
        A[2 * j]     = __builtin_bit_cast(int, __builtin_amdgcn_cvt_pkrtz(q.x, q.y));
        A[2 * j + 1] = __builtin_bit_cast(int, __builtin_amdgcn_cvt_pkrtz(q.z, q.w));
    }
    #pragma unroll
    for (int j = 0; j < 8; ++j) {
        float4 q = rp[8 + j];
        B[2 * j]     = __builtin_bit_cast(int, __builtin_amdgcn_cvt_pkrtz(q.x, q.y));
        B[2 * j + 1] = __builtin_bit_cast(int, __builtin_amdgcn_cvt_pkrtz(q.z, q.w));
    }
    return {A, B};
}

// grid = 256 blocks x 256 threads, 1 block/CU (4 waves = 1 wave/EU).
//  blocks [0,64):    LSTM rollout, wave 0 only; lane l owns all 4 gate rows of
//                    hidden unit l; hx broadcast via v_readlane; f16 fdot2.
//                    Weights pinned in VGPRs via asm anti-remat barrier
//                    (rounds 4/5: backend sank the weight loads into the loop
//                    -> dependent mem ops -> 3470 cyc/step).
//  blocks [64,192):  expert-expert MMD term (input-only, runs concurrently).
//  blocks [192,256): spin on done==64, then ll + le over COMPACTED learner pts.
__global__ __launch_bounds__(256)
__attribute__((amdgpu_waves_per_eu(1, 1)))
void fused(
    const float* __restrict__ up,    // [64,128] uniform pool
    const float* __restrict__ te,    // [64,128] expert times
    const float* __restrict__ Wih,   // [256]
    const float* __restrict__ Whh,   // [256,64]
    const float* __restrict__ bih,   // [256]
    const float* __restrict__ bhh,   // [256]
    const float* __restrict__ Vw,    // [64]
    const float* __restrict__ Vb,    // [1]
    unsigned int* __restrict__ hdr,  // ws: [0]=compacted count, [1]=done blocks
    float* __restrict__ comp,        // ws+16: compacted learner times (<=8192)
    float* __restrict__ out)         // [1] loss
{
    __shared__ float2 qbuf[2048];
    const int bid = blockIdx.x;
    const int tid = threadIdx.x;

    if (bid < 64) {
        if (tid >= 64) return;       // single wave; waves 1-3 exit (wave-uniform)
        const int l = tid;

        RowW r0 = loadrow(Whh, 0, l);
        RowW r1 = loadrow(Whh, 1, l);
        RowW r2 = loadrow(Whh, 2, l);
        RowW r3 = loadrow(Whh, 3, l);
        // Anti-remat barrier: values become opaque -> loads cannot be sunk into
        // the loop; allocator must keep all 128 VGPRs resident (budget 512).
        asm volatile("" : "+v"(r0.a), "+v"(r0.b), "+v"(r1.a), "+v"(r1.b),
                          "+v"(r2.a), "+v"(r2.b), "+v"(r3.a), "+v"(r3.b));

        float bias[4], wih[4];
        #pragma unroll
        for (int r = 0; r < 4; ++r) {
            bias[r] = bih[r * 64 + l] + bhh[r * 64 + l];
            wih[r]  = Wih[r * 64 + l];
        }
        const float vwl = Vw[l];
        const float vb  = Vb[0];
        float lu0 = -flog2(up[bid * 128 + l]) * LN2;
        float lu1 = -flog2(up[bid * 128 + 64 + l]) * LN2;

        // step 0: hx=0 -> sigma = elu(vb)+1 (elu(x)+1 == exp(x) for x<=0)
        float sg0 = (vb > 0.0f) ? (vb + 1.0f) : fexp2(vb * L2E);
        float cum = __int_as_float(__builtin_amdgcn_readlane(__float_as_int(lu0), 0)) * frcp(sg0);
        float h0 = (l == 0) ? cum : 1e30f;   // t[s] for s = l
        float h1 = 1e30f;                    // t[s] for s = 64+l
        float hx = 0.0f, cx = 0.0f;

        for (int s = 0; s < 127; ++s) {
            // pack (hx[2j], hx[2j+1]) on even lanes: quad_perm pair-swap + pkrtz
            float hxn = dppmov<0xB1>(hx);    // quad_perm [1,0,3,2]
            int hpi = __builtin_bit_cast(int, __builtin_amdgcn_cvt_pkrtz(hx, hxn));

            float d0 = 0.f, d1 = 0.f, d2 = 0.f, d3 = 0.f;
            #pragma unroll
            for (int j = 0; j < 16; ++j) {
                h2 b = __builtin_bit_cast(h2, __builtin_amdgcn_readlane(hpi, 2 * j));
                d0 = __builtin_amdgcn_fdot2(__builtin_bit_cast(h2, r0.a[j]), b, d0, false);
                d1 = __builtin_amdgcn_fdot2(__builtin_bit_cast(h2, r1.a[j]), b, d1, false);
                d2 = __builtin_amdgcn_fdot2(__builtin_bit_cast(h2, r2.a[j]), b, d2, false);
                d3 = __builtin_amdgcn_fdot2(__builtin_bit_cast(h2, r3.a[j]), b, d3, false);
            }
            #pragma unroll
            for (int j = 0; j < 16; ++j) {
                h2 b = __builtin_bit_cast(h2, __builtin_amdgcn_readlane(hpi, 32 + 2 * j));
                d0 = __builtin_amdgcn_fdot2(__builtin_bit_cast(h2, r0.b[j]), b, d0, false);
                d1 = __builtin_amdgcn_fdot2(__builtin_bit_cast(h2, r1.b[j]), b, d1, false);
                d2 = __builtin_amdgcn_fdot2(__builtin_bit_cast(h2, r2.b[j]), b, d2, false);
                d3 = __builtin_amdgcn_fdot2(__builtin_bit_cast(h2, r3.b[j]), b, d3, false);
            }
            float gi = fmaf(cum, wih[0], d0) + bias[0];
            float gf = fmaf(cum, wih[1], d1) + bias[1];
            float gg = fmaf(cum, wih[2], d2) + bias[2];
            float go = fmaf(cum, wih[3], d3) + bias[3];
            cx = fsig(gf) * cx + fsig(gi) * ftanh_(gg);
            hx = fsig(go) * ftanh_(cx);

            float tot = wsum(hx * vwl);
            float xx  = tot + vb;
            float sg  = (xx > 0.0f) ? (xx + 1.0f) : fexp2(xx * L2E);
            int idx = s + 1;
            float lun = __int_as_float(__builtin_amdgcn_readlane(
                            __float_as_int(idx < 64 ? lu0 : lu1), idx & 63));
            cum += lun * frcp(sg);
            h0 = (l == idx)      ? cum : h0;
            h1 = (l == idx - 64) ? cum : h1;
        }

        // compacted append: times monotone increasing -> actives are a prefix
        unsigned long long b0 = __ballot(h0 < TMAXV);
        unsigned long long b1 = __ballot(h1 < TMAXV);
        int n0 = __popcll(b0), n1 = __popcll(b1);
        int base = 0;
        if (l == 0) base = (int)atomicAdd(&hdr[0], (unsigned)(n0 + n1));
        base = __shfl(base, 0);
        if (h0 < TMAXV) comp[base + l] = h0;
        if (h1 < TMAXV) comp[base + 64 + l] = h1;   // only when n0==64 (monotone)
        __threadfence();
        if (l == 0) atomicAdd(&hdr[1], 1u);
    } else if (bid < 192) {
        // ---------------- expert-expert MMD term ----------------
        const int eb = bid - 64;         // 0..127
        const int pc = eb & 31;
        const int qs = eb >> 5;
        const int p = pc * 256 + tid;
        const float tp = te[p];
        const float mp = (tp < TMAXV && tp > 0.0f) ? 1.0f : 0.0f;
        const int q0 = qs * 2048;
        for (int i = tid; i < 2048; i += 256) {
            float tq = te[q0 + i];
            float mq = (tq < TMAXV && tq > 0.0f) ? 1.0f : 0.0f;
            qbuf[i] = make_float2(tq, mq);
        }
        __syncthreads();
        float acc = 0.0f;
        #pragma unroll 4
        for (int i = 0; i < 2048; ++i) {
            float2 q = qbuf[i];
            float d = tp - q.x;
            acc = fmaf(q.y, fexp2(d * d * (-L2E)), acc);
        }
        acc *= mp;
        acc = wsum_shfl(acc);
        if ((tid & 63) == 0) atomicAdd(out, acc);
    } else {
        // ---------------- ll + le on compacted learner points ----------------
        if (tid == 0) {
            while (atomicAdd(&hdr[1], 0u) < 64u) __builtin_amdgcn_s_sleep(16);
        }
        __syncthreads();
        __threadfence();   // acquire: invalidate caches before reading comp
        const int n = (int)*(volatile unsigned int*)&hdr[0];
        const int gid = (bid - 192) * 256 + tid;   // 0..16383
        const int pg = gid >> 5;                   // p-group (32 lanes each)
        const int sl = gid & 31;
        float acc = 0.0f;
        for (int pi = pg; pi < n; pi += 512) {
            float tp = comp[pi];                   // active by construction (m=1)
            float all_ = 0.0f, ale = 0.0f;
            for (int j = sl; j < 8192; j += 32) {
                float t = te[j];
                float m = (t < TMAXV && t > 0.0f) ? 1.0f : 0.0f;
                float d = tp - t;
                ale = fmaf(m, fexp2(d * d * (-L2E)), ale);
            }
            for (int j = sl; j < n; j += 32) {
                float d = tp - comp[j];
                all_ += fexp2(d * d * (-L2E));
            }
            acc += all_ - 2.0f * ale;
        }
        acc = wsum_shfl(acc);
        if ((tid & 63) == 0) atomicAdd(out, acc);
    }
}

extern "C" void kernel_launch(void* const* d_in, const int* in_sizes, int n_in,
                              void* d_out, int out_size, void* d_ws, size_t ws_size,
                              hipStream_t stream) {
    const float* up  = (const float*)d_in[0];
    const float* te  = (const float*)d_in[1];
    const float* Wih = (const float*)d_in[2];
    const float* Whh = (const float*)d_in[3];
    const float* bih = (const float*)d_in[4];
    const float* bhh = (const float*)d_in[5];
    const float* Vw  = (const float*)d_in[6];
    const float* Vb  = (const float*)d_in[7];
    unsigned int* hdr = (unsigned int*)d_ws;
    float* comp = (float*)d_ws + 4;
    float* out = (float*)d_out;

    (void)hipMemsetAsync(d_ws, 0, 16, stream);
    (void)hipMemsetAsync(d_out, 0, 4, stream);
    hipLaunchKernelGGL(fused, dim3(256), dim3(256), 0, stream,
                       up, te, Wih, Whh, bih, bhh, Vw, Vb, hdr, comp, out);
}